// Round 6
// baseline (234.260 us; speedup 1.0000x reference)
//
#include <hip/hip_runtime.h>

#define N_NODES 100000
#define N_EDGES 1000000
#define F_IN 128
#define F_HID 256
#define F_OUT 40
#define N_TILES 1563   // ceil(N_NODES / 64)
#define NB 391         // ceil(N_NODES / 256) buckets of 256 consecutive dst nodes
#define BCAP 3584      // bucket capacity: mean 2560, sigma ~50.5 -> +20 sigma
#define PART_BLOCKS 128
#define QUADS (N_EDGES / 4)                            // 250000
#define QPB ((QUADS + PART_BLOCKS - 1) / PART_BLOCKS)  // 1954
#define EPB (QPB * 4)                                  // 7816 edges/block max

typedef __attribute__((ext_vector_type(8))) short bf16x8;
typedef __attribute__((ext_vector_type(4))) float f32x4;

__device__ inline unsigned short f2bf(float f) {
    unsigned int u = __float_as_uint(f);
    return (unsigned short)((u + 0x7fffu + ((u >> 16) & 1u)) >> 16);
}
__device__ inline float bflo(unsigned int u) { return __uint_as_float(u << 16); }
__device__ inline float bfhi(unsigned int u) { return __uint_as_float(u & 0xffff0000u); }
__device__ inline unsigned int pack2(float a, float b) {
    return (unsigned int)f2bf(a) | ((unsigned int)f2bf(b) << 16);
}

// ---------------- phase 1: bucket partition, SINGLE PASS over src/dst ----------------
// LDS stash holds per-edge record + (bucket,slot) between histogram and placement.
__global__ void k_part(const int* __restrict__ src, const int* __restrict__ dst,
                       int* __restrict__ bcur, unsigned int* __restrict__ part) {
    __shared__ int h1[NB];
    __shared__ int gb[NB];
    __shared__ unsigned int st32[EPB];    // (dlocal<<17)|src
    __shared__ unsigned short st16[EPB];  // (bk<<7)|slot   (slot < 128: Poisson(20) tail safe)
    int t = threadIdx.x;
    for (int i = t; i < NB; i += 256) h1[i] = 0;
    __syncthreads();
    int q0 = blockIdx.x * QPB;
    int q1 = q0 + QPB < QUADS ? q0 + QPB : QUADS;
    for (int q = q0 + t; q < q1; q += 256) {
        int4 s4 = *(const int4*)(src + q * 4);
        int4 d4 = *(const int4*)(dst + q * 4);
        int li = (q - q0) * 4;
#pragma unroll
        for (int j = 0; j < 4; j++) {
            int d = (&d4.x)[j];
            int bk = d >> 8;
            int sl = atomicAdd(&h1[bk], 1);
            st32[li + j] = ((unsigned int)(d & 255) << 17) | (unsigned int)(&s4.x)[j];
            st16[li + j] = (unsigned short)((bk << 7) | sl);
        }
    }
    __syncthreads();
    for (int i = t; i < NB; i += 256) gb[i] = h1[i] ? atomicAdd(&bcur[i], h1[i]) : 0;
    __syncthreads();
    int nloc = (q1 - q0) * 4;
    for (int li = t; li < nloc; li += 256) {
        unsigned short w = st16[li];
        int bk = w >> 7, sl = w & 127;
        part[(size_t)bk * BCAP + gb[bk] + sl] = st32[li];
    }
}

// ---------------- phase 2: per-bucket CSR build ----------------
__global__ void k_bucket(const unsigned int* __restrict__ part, const int* __restrict__ bcur,
                         int* __restrict__ rowstart, float* __restrict__ dinv,
                         int* __restrict__ cnt, int* __restrict__ dhist,
                         int* __restrict__ esrc) {
    __shared__ int deg[256];
    __shared__ int ds[256];
    __shared__ int wsum[4];
    __shared__ int red[4];
    __shared__ int lh[64];
    __shared__ int sbase;
    int b = blockIdx.x, t = threadIdx.x;
    int lo = b * 256;
    int nn = N_NODES - lo < 256 ? N_NODES - lo : 256;
    int m = bcur[b];
    deg[t] = 0;
    if (t < 64) lh[t] = 0;
    __syncthreads();
    const unsigned int* pp = part + (size_t)b * BCAP;
    unsigned int ev[14];
    int esl[14];
#pragma unroll
    for (int k = 0; k < 14; k++) {
        int e = t + k * 256;
        if (e < m) {
            unsigned int v = pp[e];
            ev[k] = v;
            esl[k] = atomicAdd(&deg[v >> 17], 1);
        }
    }
    // base = sum of bcur[0..b)
    int partial = 0;
    for (int i = t; i < b; i += 256) partial += bcur[i];
#pragma unroll
    for (int off = 32; off; off >>= 1) partial += __shfl_down(partial, off);
    int lane = t & 63, wave = t >> 6;
    if (lane == 0) red[wave] = partial;
    __syncthreads();
    if (t == 0) sbase = red[0] + red[1] + red[2] + red[3];
    __syncthreads();
    // block scan of degrees -> absolute rowstart
    int dv = (t < nn) ? deg[t] : 0;
    int incl = dv;
#pragma unroll
    for (int off = 1; off < 64; off <<= 1) {
        int u = __shfl_up(incl, off);
        if (lane >= off) incl += u;
    }
    if (lane == 63) wsum[wave] = incl;
    __syncthreads();
    int woff = 0;
    for (int w = 0; w < wave; w++) woff += wsum[w];
    int excl = sbase + woff + incl - dv;
    if (t < nn) {
        rowstart[lo + t] = excl;
        dinv[lo + t] = rsqrtf((float)dv + 1.0f);  // +1 self-loop
        cnt[lo + t] = dv;
        ds[t] = excl;
        atomicAdd(&lh[dv < 63 ? dv : 63], 1);
    }
    if (b == NB - 1 && t == nn - 1) rowstart[N_NODES] = excl + dv;
    __syncthreads();
    if (t < 64 && lh[t]) atomicAdd(&dhist[t], lh[t]);
#pragma unroll
    for (int k = 0; k < 14; k++) {
        int e = t + k * 256;
        if (e < m) {
            unsigned int v = ev[k];
            esrc[ds[v >> 17] + esl[k]] = (int)(v & 0x1FFFFu);
        }
    }
}

// ---------------- fused: x cast + W prep + perm build (one dispatch) ----------------
__global__ void k_fill_cast(const float* __restrict__ x, const float* __restrict__ dinv,
                            uint2* __restrict__ xb,
                            const float* __restrict__ W1, const float* __restrict__ W2,
                            unsigned short* __restrict__ W1F, unsigned short* __restrict__ W2F,
                            const int* __restrict__ cnt, const int* __restrict__ dhist,
                            int* __restrict__ dcnt, int* __restrict__ perm) {
    __shared__ int lcnt[64];
    __shared__ int gb[64];
    __shared__ int db[64];
    int b = blockIdx.x;
    if (b < 12500) {
        int i = b * 256 + threadIdx.x;  // [0, 3.2M) exact
        float4 v = ((const float4*)x)[i];
        float d = dinv[i >> 5];  // node = i*4/128
        xb[i] = make_uint2(pack2(d * v.x, d * v.y), pack2(d * v.z, d * v.w));
    } else if (b < 12692) {
        int i = (b - 12500) * 256 + threadIdx.x;  // [0, 49152)
        if (i < 32768) {
            int j = i & 7, lane = (i >> 3) & 63, mt = (i >> 9) & 7, kc = (i >> 12) & 3, mhalf = i >> 14;
            int l16 = lane & 15, quad = lane >> 4;
            int n = mhalf * 128 + mt * 16 + l16;
            int k = kc * 32 + quad * 8 + j;
            W1F[i] = f2bf(W1[k * F_HID + n]);
        } else {
            int i2 = i - 32768;
            int j = i2 & 7, lane = (i2 >> 3) & 63, mt = (i2 >> 9) & 3, kc = i2 >> 11;
            int l16 = lane & 15, quad = lane >> 4;
            int n = mt * 16 + l16;
            int k = kc * 32 + quad * 8 + j;
            W2F[i2] = (n < F_OUT) ? f2bf(W2[k * F_OUT + n]) : (unsigned short)0;
        }
    } else {
        // perm build: counting sort by clamped degree, descending (heavy first)
        int t = threadIdx.x;
        if (t < 64) {
            lcnt[t] = 0;
            int val = dhist[63 - t];
            int incl = val;
#pragma unroll
            for (int off = 1; off < 64; off <<= 1) {
                int u = __shfl_up(incl, off);
                if (t >= off) incl += u;
            }
            db[63 - t] = incl - val;
        }
        __syncthreads();
        int nb0 = (b - 12692) * 1024;
        int bk[4], sl[4];
#pragma unroll
        for (int j = 0; j < 4; j++) {
            int i = nb0 + t * 4 + j;
            if (i < N_NODES) {
                int d = cnt[i];
                bk[j] = d < 63 ? d : 63;
                sl[j] = atomicAdd(&lcnt[bk[j]], 1);
            }
        }
        __syncthreads();
        if (t < 64) gb[t] = lcnt[t] ? atomicAdd(&dcnt[t], lcnt[t]) : 0;
        __syncthreads();
#pragma unroll
        for (int j = 0; j < 4; j++) {
            int i = nb0 + t * 4 + j;
            if (i < N_NODES) perm[db[bk[j]] + gb[bk[j]] + sl[j]] = i;
        }
    }
}

// ---------------- FUSED layer-1 aggregation + both GEMMs ----------------
// Phase A: 16 lane-groups x 4 nodes aggregate the block's 64 perm-rows into LDS
//          (MFMA fragment order) -- no global xagg round trip.
// Phase B: h2s = bf16( dinv * (relu(xagg@W1+b1) @ W2) ), scatter to h2b[perm[row]].
__launch_bounds__(256)
__global__ void k_agg_gemm(const uint4* __restrict__ xb4, const float* __restrict__ dinv,
                           const int* __restrict__ rowstart, const int* __restrict__ esrc,
                           const int* __restrict__ perm,
                           const unsigned short* __restrict__ W1F,
                           const unsigned short* __restrict__ W2F,
                           const float* __restrict__ b1,
                           unsigned short* __restrict__ h2b) {
    __shared__ __align__(16) unsigned short xaggL[8192];   // 64x128 bf16, fragment order
    __shared__ __align__(16) unsigned short Hs[64][268];   // stride 268: <=2-way conflicts
    int tid = threadIdx.x;

    // ---- phase A ----
    {
        int group = tid >> 4;
        int l16 = tid & 15;
        int kc = l16 >> 2;
        int quad = l16 & 3;
        for (int it = 0; it < 4; ++it) {
            int row_local = it * 16 + group;
            int r = blockIdx.x * 64 + row_local;
            float a0 = 0.f, a1 = 0.f, a2 = 0.f, a3 = 0.f,
                  a4 = 0.f, a5 = 0.f, a6 = 0.f, a7 = 0.f;
            if (r < N_NODES) {
                int node = perm[r];
                uint4 v = xb4[(size_t)node * 16 + l16];
                a0 = bflo(v.x); a1 = bfhi(v.x); a2 = bflo(v.y); a3 = bfhi(v.y);
                a4 = bflo(v.z); a5 = bfhi(v.z); a6 = bflo(v.w); a7 = bfhi(v.w);
                int e0 = rowstart[node];
                int e1 = rowstart[node + 1];
                int e = e0;
                int p0, p1, p2, p3, p4, p5, p6, p7;
                if (e + 7 < e1) {
                    p0 = esrc[e];     p1 = esrc[e + 1]; p2 = esrc[e + 2]; p3 = esrc[e + 3];
                    p4 = esrc[e + 4]; p5 = esrc[e + 5]; p6 = esrc[e + 6]; p7 = esrc[e + 7];
                }
                while (e + 7 < e1) {
                    int s0 = p0, s1 = p1, s2 = p2, s3 = p3, s4 = p4, s5 = p5, s6 = p6, s7 = p7;
                    e += 8;
                    if (e + 7 < e1) {
                        p0 = esrc[e];     p1 = esrc[e + 1]; p2 = esrc[e + 2]; p3 = esrc[e + 3];
                        p4 = esrc[e + 4]; p5 = esrc[e + 5]; p6 = esrc[e + 6]; p7 = esrc[e + 7];
                    }
                    uint4 u0 = xb4[(size_t)s0 * 16 + l16];
                    uint4 u1 = xb4[(size_t)s1 * 16 + l16];
                    uint4 u2 = xb4[(size_t)s2 * 16 + l16];
                    uint4 u3 = xb4[(size_t)s3 * 16 + l16];
                    uint4 u4 = xb4[(size_t)s4 * 16 + l16];
                    uint4 u5 = xb4[(size_t)s5 * 16 + l16];
                    uint4 u6 = xb4[(size_t)s6 * 16 + l16];
                    uint4 u7 = xb4[(size_t)s7 * 16 + l16];
                    a0 += bflo(u0.x) + bflo(u1.x) + bflo(u2.x) + bflo(u3.x);
                    a0 += bflo(u4.x) + bflo(u5.x) + bflo(u6.x) + bflo(u7.x);
                    a1 += bfhi(u0.x) + bfhi(u1.x) + bfhi(u2.x) + bfhi(u3.x);
                    a1 += bfhi(u4.x) + bfhi(u5.x) + bfhi(u6.x) + bfhi(u7.x);
                    a2 += bflo(u0.y) + bflo(u1.y) + bflo(u2.y) + bflo(u3.y);
                    a2 += bflo(u4.y) + bflo(u5.y) + bflo(u6.y) + bflo(u7.y);
                    a3 += bfhi(u0.y) + bfhi(u1.y) + bfhi(u2.y) + bfhi(u3.y);
                    a3 += bfhi(u4.y) + bfhi(u5.y) + bfhi(u6.y) + bfhi(u7.y);
                    a4 += bflo(u0.z) + bflo(u1.z) + bflo(u2.z) + bflo(u3.z);
                    a4 += bflo(u4.z) + bflo(u5.z) + bflo(u6.z) + bflo(u7.z);
                    a5 += bfhi(u0.z) + bfhi(u1.z) + bfhi(u2.z) + bfhi(u3.z);
                    a5 += bfhi(u4.z) + bfhi(u5.z) + bfhi(u6.z) + bfhi(u7.z);
                    a6 += bflo(u0.w) + bflo(u1.w) + bflo(u2.w) + bflo(u3.w);
                    a6 += bflo(u4.w) + bflo(u5.w) + bflo(u6.w) + bflo(u7.w);
                    a7 += bfhi(u0.w) + bfhi(u1.w) + bfhi(u2.w) + bfhi(u3.w);
                    a7 += bfhi(u4.w) + bfhi(u5.w) + bfhi(u6.w) + bfhi(u7.w);
                }
                if (e + 3 < e1) {
                    int s0 = esrc[e], s1 = esrc[e + 1], s2 = esrc[e + 2], s3 = esrc[e + 3];
                    e += 4;
                    uint4 u0 = xb4[(size_t)s0 * 16 + l16];
                    uint4 u1 = xb4[(size_t)s1 * 16 + l16];
                    uint4 u2 = xb4[(size_t)s2 * 16 + l16];
                    uint4 u3 = xb4[(size_t)s3 * 16 + l16];
                    a0 += bflo(u0.x) + bflo(u1.x) + bflo(u2.x) + bflo(u3.x);
                    a1 += bfhi(u0.x) + bfhi(u1.x) + bfhi(u2.x) + bfhi(u3.x);
                    a2 += bflo(u0.y) + bflo(u1.y) + bflo(u2.y) + bflo(u3.y);
                    a3 += bfhi(u0.y) + bfhi(u1.y) + bfhi(u2.y) + bfhi(u3.y);
                    a4 += bflo(u0.z) + bflo(u1.z) + bflo(u2.z) + bflo(u3.z);
                    a5 += bfhi(u0.z) + bfhi(u1.z) + bfhi(u2.z) + bfhi(u3.z);
                    a6 += bflo(u0.w) + bflo(u1.w) + bflo(u2.w) + bflo(u3.w);
                    a7 += bfhi(u0.w) + bfhi(u1.w) + bfhi(u2.w) + bfhi(u3.w);
                }
                for (; e < e1; ++e) {
                    uint4 u = xb4[(size_t)esrc[e] * 16 + l16];
                    a0 += bflo(u.x); a1 += bfhi(u.x); a2 += bflo(u.y); a3 += bfhi(u.y);
                    a4 += bflo(u.z); a5 += bfhi(u.z); a6 += bflo(u.w); a7 += bfhi(u.w);
                }
                float di = dinv[node];
                a0 *= di; a1 *= di; a2 *= di; a3 *= di;
                a4 *= di; a5 *= di; a6 *= di; a7 *= di;
            }
            int nhalf = row_local >> 5, nt = (row_local >> 4) & 1, l16r = row_local & 15;
            int off = (kc * 4 + nhalf * 2 + nt) * 512 + (quad * 16 + l16r) * 8;
            *(uint4*)(xaggL + off) = make_uint4(pack2(a0, a1), pack2(a2, a3),
                                                pack2(a4, a5), pack2(a6, a7));
        }
    }
    __syncthreads();

    // ---- phase B ----
    int w = tid >> 6, lane = tid & 63;
    int quad = lane >> 4, l16 = lane & 15;
    int row0 = blockIdx.x * 64;
    int mhalf = w >> 1;
    int nhalf = w & 1;

    f32x4 acc[2][8];
#pragma unroll
    for (int nt = 0; nt < 2; nt++)
#pragma unroll
        for (int mt = 0; mt < 8; mt++) acc[nt][mt] = (f32x4){0.f, 0.f, 0.f, 0.f};

#pragma unroll
    for (int kc = 0; kc < 4; ++kc) {
        bf16x8 bf[2], af[8];
#pragma unroll
        for (int nt = 0; nt < 2; nt++)
            bf[nt] = *(const bf16x8*)(xaggL + (size_t)(kc * 4 + nhalf * 2 + nt) * 512 + lane * 8);
#pragma unroll
        for (int mt = 0; mt < 8; mt++)
            af[mt] = *(const bf16x8*)(W1F + (size_t)((mhalf * 4 + kc) * 8 + mt) * 512 + lane * 8);
#pragma unroll
        for (int nt = 0; nt < 2; nt++)
#pragma unroll
            for (int mt = 0; mt < 8; mt++)
                acc[nt][mt] = __builtin_amdgcn_mfma_f32_16x16x32_bf16(af[mt], bf[nt], acc[nt][mt], 0, 0, 0);
    }
#pragma unroll
    for (int mt = 0; mt < 8; mt++) {
        int colbase = mhalf * 128 + mt * 16 + quad * 4;
        float4 bb = *(const float4*)(b1 + colbase);
#pragma unroll
        for (int nt = 0; nt < 2; nt++) {
            int nrow = nhalf * 32 + nt * 16 + l16;
            float v0 = fmaxf(acc[nt][mt][0] + bb.x, 0.f);
            float v1 = fmaxf(acc[nt][mt][1] + bb.y, 0.f);
            float v2 = fmaxf(acc[nt][mt][2] + bb.z, 0.f);
            float v3 = fmaxf(acc[nt][mt][3] + bb.w, 0.f);
            *(uint2*)&Hs[nrow][colbase] = make_uint2(pack2(v0, v1), pack2(v2, v3));
        }
    }
    __syncthreads();

    f32x4 acc2[4];
#pragma unroll
    for (int mt = 0; mt < 4; mt++) acc2[mt] = (f32x4){0.f, 0.f, 0.f, 0.f};
#pragma unroll
    for (int kc = 0; kc < 8; ++kc) {
        int k0 = kc * 32;
        uint2 hlo = *(const uint2*)&Hs[w * 16 + l16][k0 + quad * 8];
        uint2 hhi = *(const uint2*)&Hs[w * 16 + l16][k0 + quad * 8 + 4];
        union { uint4 u; bf16x8 b; } hc;
        hc.u = make_uint4(hlo.x, hlo.y, hhi.x, hhi.y);
        bf16x8 hf = hc.b;
        bf16x8 wf[4];
#pragma unroll
        for (int mt = 0; mt < 4; mt++)
            wf[mt] = *(const bf16x8*)(W2F + (size_t)(kc * 4 + mt) * 512 + lane * 8);
#pragma unroll
        for (int mt = 0; mt < 4; mt++)
            acc2[mt] = __builtin_amdgcn_mfma_f32_16x16x32_bf16(wf[mt], hf, acc2[mt], 0, 0, 0);
    }
    int grow = row0 + w * 16 + l16;  // perm position
    if (grow < N_NODES) {
        int node = perm[grow];
        float dg = dinv[node];
#pragma unroll
        for (int mt = 0; mt < 3; mt++) {  // only cols < 40 stored (stride-40 h2b)
            int col = mt * 16 + quad * 4;
            if (col < F_OUT) {
                uint2 o = make_uint2(pack2(dg * acc2[mt][0], dg * acc2[mt][1]),
                                     pack2(dg * acc2[mt][2], dg * acc2[mt][3]));
                *(uint2*)(h2b + (size_t)node * 40 + col) = o;
            }
        }
    }
}

// ---------------- layer 2 aggregation + bias + log_softmax ----------------
// 5 lanes/node (60/64 active), 12 nodes/wave, 48 nodes/block; pipelined 8-edge unroll.
__global__ void k_agg2(const uint4* __restrict__ h2v4, const float* __restrict__ dinv,
                       const int* __restrict__ rowstart,
                       const int* __restrict__ esrc, const int* __restrict__ perm,
                       const float* __restrict__ b2, float* __restrict__ out) {
    int t = threadIdx.x;
    int wv = t >> 6, lane = t & 63;
    int grp = lane / 5;          // 0..11 active, 12 = lanes 60..63 idle
    int c = lane - grp * 5;      // chunk 0..4
    int r = blockIdx.x * 48 + wv * 12 + grp;
    bool act = (grp < 12) && (r < N_NODES);
    int node = act ? perm[r] : 0;
    float a0 = 0.f, a1 = 0.f, a2 = 0.f, a3 = 0.f, a4 = 0.f, a5 = 0.f, a6 = 0.f, a7 = 0.f;
    if (act) {
        uint4 v = h2v4[(size_t)node * 5 + c];  // self term (pre-scaled)
        a0 = bflo(v.x); a1 = bfhi(v.x); a2 = bflo(v.y); a3 = bfhi(v.y);
        a4 = bflo(v.z); a5 = bfhi(v.z); a6 = bflo(v.w); a7 = bfhi(v.w);
        int e0 = rowstart[node];
        int e1 = rowstart[node + 1];
        int e = e0;
        int p0, p1, p2, p3, p4, p5, p6, p7;
        if (e + 7 < e1) {
            p0 = esrc[e];     p1 = esrc[e + 1]; p2 = esrc[e + 2]; p3 = esrc[e + 3];
            p4 = esrc[e + 4]; p5 = esrc[e + 5]; p6 = esrc[e + 6]; p7 = esrc[e + 7];
        }
        while (e + 7 < e1) {
            int s0 = p0, s1 = p1, s2 = p2, s3 = p3, s4 = p4, s5 = p5, s6 = p6, s7 = p7;
            e += 8;
            if (e + 7 < e1) {
                p0 = esrc[e];     p1 = esrc[e + 1]; p2 = esrc[e + 2]; p3 = esrc[e + 3];
                p4 = esrc[e + 4]; p5 = esrc[e + 5]; p6 = esrc[e + 6]; p7 = esrc[e + 7];
            }
            uint4 u0 = h2v4[(size_t)s0 * 5 + c];
            uint4 u1 = h2v4[(size_t)s1 * 5 + c];
            uint4 u2 = h2v4[(size_t)s2 * 5 + c];
            uint4 u3 = h2v4[(size_t)s3 * 5 + c];
            uint4 u4 = h2v4[(size_t)s4 * 5 + c];
            uint4 u5 = h2v4[(size_t)s5 * 5 + c];
            uint4 u6 = h2v4[(size_t)s6 * 5 + c];
            uint4 u7 = h2v4[(size_t)s7 * 5 + c];
            a0 += bflo(u0.x) + bflo(u1.x) + bflo(u2.x) + bflo(u3.x);
            a0 += bflo(u4.x) + bflo(u5.x) + bflo(u6.x) + bflo(u7.x);
            a1 += bfhi(u0.x) + bfhi(u1.x) + bfhi(u2.x) + bfhi(u3.x);
            a1 += bfhi(u4.x) + bfhi(u5.x) + bfhi(u6.x) + bfhi(u7.x);
            a2 += bflo(u0.y) + bflo(u1.y) + bflo(u2.y) + bflo(u3.y);
            a2 += bflo(u4.y) + bflo(u5.y) + bflo(u6.y) + bflo(u7.y);
            a3 += bfhi(u0.y) + bfhi(u1.y) + bfhi(u2.y) + bfhi(u3.y);
            a3 += bfhi(u4.y) + bfhi(u5.y) + bfhi(u6.y) + bfhi(u7.y);
            a4 += bflo(u0.z) + bflo(u1.z) + bflo(u2.z) + bflo(u3.z);
            a4 += bflo(u4.z) + bflo(u5.z) + bflo(u6.z) + bflo(u7.z);
            a5 += bfhi(u0.z) + bfhi(u1.z) + bfhi(u2.z) + bfhi(u3.z);
            a5 += bfhi(u4.z) + bfhi(u5.z) + bfhi(u6.z) + bfhi(u7.z);
            a6 += bflo(u0.w) + bflo(u1.w) + bflo(u2.w) + bflo(u3.w);
            a6 += bflo(u4.w) + bflo(u5.w) + bflo(u6.w) + bflo(u7.w);
            a7 += bfhi(u0.w) + bfhi(u1.w) + bfhi(u2.w) + bfhi(u3.w);
            a7 += bfhi(u4.w) + bfhi(u5.w) + bfhi(u6.w) + bfhi(u7.w);
        }
        if (e + 3 < e1) {
            int s0 = esrc[e], s1 = esrc[e + 1], s2 = esrc[e + 2], s3 = esrc[e + 3];
            e += 4;
            uint4 u0 = h2v4[(size_t)s0 * 5 + c];
            uint4 u1 = h2v4[(size_t)s1 * 5 + c];
            uint4 u2 = h2v4[(size_t)s2 * 5 + c];
            uint4 u3 = h2v4[(size_t)s3 * 5 + c];
            a0 += bflo(u0.x) + bflo(u1.x) + bflo(u2.x) + bflo(u3.x);
            a1 += bfhi(u0.x) + bfhi(u1.x) + bfhi(u2.x) + bfhi(u3.x);
            a2 += bflo(u0.y) + bflo(u1.y) + bflo(u2.y) + bflo(u3.y);
            a3 += bfhi(u0.y) + bfhi(u1.y) + bfhi(u2.y) + bfhi(u3.y);
            a4 += bflo(u0.z) + bflo(u1.z) + bflo(u2.z) + bflo(u3.z);
            a5 += bfhi(u0.z) + bfhi(u1.z) + bfhi(u2.z) + bfhi(u3.z);
            a6 += bflo(u0.w) + bflo(u1.w) + bflo(u2.w) + bflo(u3.w);
            a7 += bfhi(u0.w) + bfhi(u1.w) + bfhi(u2.w) + bfhi(u3.w);
        }
        for (; e < e1; ++e) {
            uint4 u = h2v4[(size_t)esrc[e] * 5 + c];
            a0 += bflo(u.x); a1 += bfhi(u.x); a2 += bflo(u.y); a3 += bfhi(u.y);
            a4 += bflo(u.z); a5 += bfhi(u.z); a6 += bflo(u.w); a7 += bfhi(u.w);
        }
    }
    float di = dinv[node];
    float vals[8];
    if (act) {
        float4 bA = *(const float4*)(b2 + 8 * c);
        float4 bB = *(const float4*)(b2 + 8 * c + 4);
        vals[0] = di * a0 + bA.x; vals[1] = di * a1 + bA.y;
        vals[2] = di * a2 + bA.z; vals[3] = di * a3 + bA.w;
        vals[4] = di * a4 + bB.x; vals[5] = di * a5 + bB.y;
        vals[6] = di * a6 + bB.z; vals[7] = di * a7 + bB.w;
    } else {
#pragma unroll
        for (int j = 0; j < 8; j++) vals[j] = -3.0e38f;
    }
    float pm = vals[0];
#pragma unroll
    for (int j = 1; j < 8; j++) pm = fmaxf(pm, vals[j]);
    float m = pm;
#pragma unroll
    for (int k = 1; k < 5; k++) {
        int srcl = grp * 5 + ((c + k) % 5);
        srcl = srcl > 63 ? 63 : srcl;
        m = fmaxf(m, __shfl(pm, srcl));
    }
    float ps = 0.0f;
    if (act) {
#pragma unroll
        for (int j = 0; j < 8; j++) ps += __expf(vals[j] - m);
    }
    float s = ps;
#pragma unroll
    for (int k = 1; k < 5; k++) {
        int srcl = grp * 5 + ((c + k) % 5);
        srcl = srcl > 63 ? 63 : srcl;
        s += __shfl(ps, srcl);
    }
    float logs = logf(s);
    if (act) {
        float o0[4] = {vals[0] - m - logs, vals[1] - m - logs, vals[2] - m - logs, vals[3] - m - logs};
        float o1[4] = {vals[4] - m - logs, vals[5] - m - logs, vals[6] - m - logs, vals[7] - m - logs};
        float* ob = out + (size_t)node * F_OUT + 8 * c;
        *(float4*)ob = *(float4*)o0;
        *(float4*)(ob + 4) = *(float4*)o1;
    }
}

// ---------------- launch ----------------

extern "C" void kernel_launch(void* const* d_in, const int* in_sizes, int n_in,
                              void* d_out, int out_size, void* d_ws, size_t ws_size,
                              hipStream_t stream) {
    const float* x  = (const float*)d_in[0];
    const int* edge = (const int*)d_in[1];
    const float* W1 = (const float*)d_in[2];
    const float* b1 = (const float*)d_in[3];
    const float* W2 = (const float*)d_in[4];
    const float* b2 = (const float*)d_in[5];
    float* out = (float*)d_out;
    const int* src = edge;
    const int* dst = edge + N_EDGES;

    char* ws = (char*)d_ws;
    size_t off = 0;
    auto alloc = [&](size_t bytes) -> void* {
        void* p = ws + off;
        off = (off + bytes + 255) & ~(size_t)255;
        return p;
    };
    int* bcur     = (int*)alloc((size_t)(NB + 128) * 4);  // bcur[NB] + dhist[64] + dcnt[64]
    int* dhist    = bcur + NB;
    int* dcnt     = bcur + NB + 64;
    unsigned int* part = (unsigned int*)alloc((size_t)NB * BCAP * 4);
    float* dinv   = (float*)alloc((size_t)N_NODES * 4);
    int* cnt      = (int*)alloc((size_t)N_NODES * 4);
    int* rowstart = (int*)alloc((size_t)(N_NODES + 1) * 4);
    int* perm     = (int*)alloc((size_t)N_NODES * 4);
    int* esrc     = (int*)alloc((size_t)N_EDGES * 4);
    unsigned int* xb       = (unsigned int*)alloc((size_t)N_NODES * F_IN * 2);
    unsigned short* W1F    = (unsigned short*)alloc((size_t)32768 * 2);
    unsigned short* W2F    = (unsigned short*)alloc((size_t)16384 * 2);
    unsigned short* h2b    = (unsigned short*)alloc((size_t)N_NODES * 40 * 2);  // stride-40
    (void)ws_size; (void)in_sizes; (void)n_in; (void)out_size;

    hipMemsetAsync(bcur, 0, (size_t)(NB + 128) * 4, stream);
    hipLaunchKernelGGL(k_part, dim3(PART_BLOCKS), dim3(256), 0, stream,
                       src, dst, bcur, part);
    hipLaunchKernelGGL(k_bucket, dim3(NB), dim3(256), 0, stream,
                       part, bcur, rowstart, dinv, cnt, dhist, esrc);
    hipLaunchKernelGGL(k_fill_cast, dim3(12790), dim3(256), 0, stream,
                       x, dinv, (uint2*)xb, W1, W2, W1F, W2F, cnt, dhist, dcnt, perm);
    hipLaunchKernelGGL(k_agg_gemm, dim3(N_TILES), dim3(256), 0, stream,
                       (const uint4*)xb, dinv, rowstart, esrc, perm, W1F, W2F, b1, h2b);
    hipLaunchKernelGGL(k_agg2, dim3((N_NODES + 47) / 48), dim3(256), 0, stream,
                       (const uint4*)h2b, dinv, rowstart, esrc, perm, b2, out);
}

// Round 7
// 225.733 us; speedup vs baseline: 1.0378x; 1.0378x over previous
//
#include <hip/hip_runtime.h>

#define N_NODES 100000
#define N_EDGES 1000000
#define F_IN 128
#define F_HID 256
#define F_OUT 40
#define N_TILES 1563   // ceil(N_NODES / 64)
#define NB 391         // ceil(N_NODES / 256) buckets of 256 consecutive dst nodes
#define BCAP 3584      // bucket capacity: mean 2560, sigma ~50.5 -> +20 sigma
#define PART_BLOCKS 128
#define QUADS (N_EDGES / 4)                            // 250000
#define QPB ((QUADS + PART_BLOCKS - 1) / PART_BLOCKS)  // 1954
#define EPB (QPB * 4)                                  // 7816 edges/block max

typedef __attribute__((ext_vector_type(8))) short bf16x8;
typedef __attribute__((ext_vector_type(4))) float f32x4;

__device__ inline unsigned short f2bf(float f) {
    unsigned int u = __float_as_uint(f);
    return (unsigned short)((u + 0x7fffu + ((u >> 16) & 1u)) >> 16);
}
__device__ inline float bflo(unsigned int u) { return __uint_as_float(u << 16); }
__device__ inline float bfhi(unsigned int u) { return __uint_as_float(u & 0xffff0000u); }
__device__ inline unsigned int pack2(float a, float b) {
    return (unsigned int)f2bf(a) | ((unsigned int)f2bf(b) << 16);
}

// ---------------- phase 1: bucket partition, SINGLE PASS over src/dst ----------------
__global__ void k_part(const int* __restrict__ src, const int* __restrict__ dst,
                       int* __restrict__ bcur, unsigned int* __restrict__ part) {
    __shared__ int h1[NB];
    __shared__ int gb[NB];
    __shared__ unsigned int st32[EPB];    // (dlocal<<17)|src
    __shared__ unsigned short st16[EPB];  // (bk<<7)|slot
    int t = threadIdx.x;
    for (int i = t; i < NB; i += 256) h1[i] = 0;
    __syncthreads();
    int q0 = blockIdx.x * QPB;
    int q1 = q0 + QPB < QUADS ? q0 + QPB : QUADS;
    for (int q = q0 + t; q < q1; q += 256) {
        int4 s4 = *(const int4*)(src + q * 4);
        int4 d4 = *(const int4*)(dst + q * 4);
        int li = (q - q0) * 4;
#pragma unroll
        for (int j = 0; j < 4; j++) {
            int d = (&d4.x)[j];
            int bk = d >> 8;
            int sl = atomicAdd(&h1[bk], 1);
            st32[li + j] = ((unsigned int)(d & 255) << 17) | (unsigned int)(&s4.x)[j];
            st16[li + j] = (unsigned short)((bk << 7) | sl);
        }
    }
    __syncthreads();
    for (int i = t; i < NB; i += 256) gb[i] = h1[i] ? atomicAdd(&bcur[i], h1[i]) : 0;
    __syncthreads();
    int nloc = (q1 - q0) * 4;
    for (int li = t; li < nloc; li += 256) {
        unsigned short w = st16[li];
        int bk = w >> 7, sl = w & 127;
        part[(size_t)bk * BCAP + gb[bk] + sl] = st32[li];
    }
}

// ---------------- phase 2: per-bucket CSR build ----------------
__global__ void k_bucket(const unsigned int* __restrict__ part, const int* __restrict__ bcur,
                         int* __restrict__ rowstart, float* __restrict__ dinv,
                         int* __restrict__ cnt, int* __restrict__ dhist,
                         int* __restrict__ esrc) {
    __shared__ int deg[256];
    __shared__ int ds[256];
    __shared__ int wsum[4];
    __shared__ int red[4];
    __shared__ int lh[64];
    __shared__ int sbase;
    int b = blockIdx.x, t = threadIdx.x;
    int lo = b * 256;
    int nn = N_NODES - lo < 256 ? N_NODES - lo : 256;
    int m = bcur[b];
    deg[t] = 0;
    if (t < 64) lh[t] = 0;
    __syncthreads();
    const unsigned int* pp = part + (size_t)b * BCAP;
    unsigned int ev[14];
    int esl[14];
#pragma unroll
    for (int k = 0; k < 14; k++) {
        int e = t + k * 256;
        if (e < m) {
            unsigned int v = pp[e];
            ev[k] = v;
            esl[k] = atomicAdd(&deg[v >> 17], 1);
        }
    }
    int partial = 0;
    for (int i = t; i < b; i += 256) partial += bcur[i];
#pragma unroll
    for (int off = 32; off; off >>= 1) partial += __shfl_down(partial, off);
    int lane = t & 63, wave = t >> 6;
    if (lane == 0) red[wave] = partial;
    __syncthreads();
    if (t == 0) sbase = red[0] + red[1] + red[2] + red[3];
    __syncthreads();
    int dv = (t < nn) ? deg[t] : 0;
    int incl = dv;
#pragma unroll
    for (int off = 1; off < 64; off <<= 1) {
        int u = __shfl_up(incl, off);
        if (lane >= off) incl += u;
    }
    if (lane == 63) wsum[wave] = incl;
    __syncthreads();
    int woff = 0;
    for (int w = 0; w < wave; w++) woff += wsum[w];
    int excl = sbase + woff + incl - dv;
    if (t < nn) {
        rowstart[lo + t] = excl;
        dinv[lo + t] = rsqrtf((float)dv + 1.0f);  // +1 self-loop
        cnt[lo + t] = dv;
        ds[t] = excl;
        atomicAdd(&lh[dv < 63 ? dv : 63], 1);
    }
    if (b == NB - 1 && t == nn - 1) rowstart[N_NODES] = excl + dv;
    __syncthreads();
    if (t < 64 && lh[t]) atomicAdd(&dhist[t], lh[t]);
#pragma unroll
    for (int k = 0; k < 14; k++) {
        int e = t + k * 256;
        if (e < m) {
            unsigned int v = ev[k];
            esrc[ds[v >> 17] + esl[k]] = (int)(v & 0x1FFFFu);
        }
    }
}

// ---------------- fused: x cast + W prep + perm build (one dispatch) ----------------
__global__ void k_fill_cast(const float* __restrict__ x, const float* __restrict__ dinv,
                            uint2* __restrict__ xb,
                            const float* __restrict__ W1, const float* __restrict__ W2,
                            unsigned short* __restrict__ W1F, unsigned short* __restrict__ W2F,
                            const int* __restrict__ cnt, const int* __restrict__ dhist,
                            int* __restrict__ dcnt, int* __restrict__ perm) {
    __shared__ int lcnt[64];
    __shared__ int gb[64];
    __shared__ int db[64];
    int b = blockIdx.x;
    if (b < 12500) {
        int i = b * 256 + threadIdx.x;  // [0, 3.2M) exact
        float4 v = ((const float4*)x)[i];
        float d = dinv[i >> 5];  // node = i*4/128
        xb[i] = make_uint2(pack2(d * v.x, d * v.y), pack2(d * v.z, d * v.w));
    } else if (b < 12692) {
        int i = (b - 12500) * 256 + threadIdx.x;  // [0, 49152)
        if (i < 32768) {
            int j = i & 7, lane = (i >> 3) & 63, mt = (i >> 9) & 7, kc = (i >> 12) & 3, mhalf = i >> 14;
            int l16 = lane & 15, quad = lane >> 4;
            int n = mhalf * 128 + mt * 16 + l16;
            int k = kc * 32 + quad * 8 + j;
            W1F[i] = f2bf(W1[k * F_HID + n]);
        } else {
            int i2 = i - 32768;
            int j = i2 & 7, lane = (i2 >> 3) & 63, mt = (i2 >> 9) & 3, kc = i2 >> 11;
            int l16 = lane & 15, quad = lane >> 4;
            int n = mt * 16 + l16;
            int k = kc * 32 + quad * 8 + j;
            W2F[i2] = (n < F_OUT) ? f2bf(W2[k * F_OUT + n]) : (unsigned short)0;
        }
    } else {
        // perm build: counting sort by clamped degree, descending (heavy first)
        int t = threadIdx.x;
        if (t < 64) {
            lcnt[t] = 0;
            int val = dhist[63 - t];
            int incl = val;
#pragma unroll
            for (int off = 1; off < 64; off <<= 1) {
                int u = __shfl_up(incl, off);
                if (t >= off) incl += u;
            }
            db[63 - t] = incl - val;
        }
        __syncthreads();
        int nb0 = (b - 12692) * 1024;
        int bk[4], sl[4];
#pragma unroll
        for (int j = 0; j < 4; j++) {
            int i = nb0 + t * 4 + j;
            if (i < N_NODES) {
                int d = cnt[i];
                bk[j] = d < 63 ? d : 63;
                sl[j] = atomicAdd(&lcnt[bk[j]], 1);
            }
        }
        __syncthreads();
        if (t < 64) gb[t] = lcnt[t] ? atomicAdd(&dcnt[t], lcnt[t]) : 0;
        __syncthreads();
#pragma unroll
        for (int j = 0; j < 4; j++) {
            int i = nb0 + t * 4 + j;
            if (i < N_NODES) perm[db[bk[j]] + gb[bk[j]] + sl[j]] = i;
        }
    }
}

// ---------------- layer 1 aggregation: 16 lanes/node, perm-ordered, pipelined 8-edge unroll ----------------
__global__ void k_agg1(const uint4* __restrict__ xb4, const float* __restrict__ dinv,
                       const int* __restrict__ rowstart,
                       const int* __restrict__ esrc, const int* __restrict__ perm,
                       unsigned short* __restrict__ xaggF) {
    int group = threadIdx.x >> 4;  // 16 groups/block
    int l16 = threadIdx.x & 15;
    int kc = l16 >> 2;
    int quad = l16 & 3;
    int r = blockIdx.x * 16 + group;  // perm position, < 100000 exact
    int node = perm[r];

    uint4 v = xb4[(size_t)node * 16 + l16];
    float a0 = bflo(v.x), a1 = bfhi(v.x), a2 = bflo(v.y), a3 = bfhi(v.y);
    float a4 = bflo(v.z), a5 = bfhi(v.z), a6 = bflo(v.w), a7 = bfhi(v.w);
    int e0 = rowstart[node];
    int e1 = rowstart[node + 1];
    int e = e0;
    int p0, p1, p2, p3, p4, p5, p6, p7;
    if (e + 7 < e1) {
        p0 = esrc[e];     p1 = esrc[e + 1]; p2 = esrc[e + 2]; p3 = esrc[e + 3];
        p4 = esrc[e + 4]; p5 = esrc[e + 5]; p6 = esrc[e + 6]; p7 = esrc[e + 7];
    }
    while (e + 7 < e1) {
        int s0 = p0, s1 = p1, s2 = p2, s3 = p3, s4 = p4, s5 = p5, s6 = p6, s7 = p7;
        e += 8;
        if (e + 7 < e1) {
            p0 = esrc[e];     p1 = esrc[e + 1]; p2 = esrc[e + 2]; p3 = esrc[e + 3];
            p4 = esrc[e + 4]; p5 = esrc[e + 5]; p6 = esrc[e + 6]; p7 = esrc[e + 7];
        }
        uint4 u0 = xb4[(size_t)s0 * 16 + l16];
        uint4 u1 = xb4[(size_t)s1 * 16 + l16];
        uint4 u2 = xb4[(size_t)s2 * 16 + l16];
        uint4 u3 = xb4[(size_t)s3 * 16 + l16];
        uint4 u4 = xb4[(size_t)s4 * 16 + l16];
        uint4 u5 = xb4[(size_t)s5 * 16 + l16];
        uint4 u6 = xb4[(size_t)s6 * 16 + l16];
        uint4 u7 = xb4[(size_t)s7 * 16 + l16];
        a0 += bflo(u0.x) + bflo(u1.x) + bflo(u2.x) + bflo(u3.x);
        a0 += bflo(u4.x) + bflo(u5.x) + bflo(u6.x) + bflo(u7.x);
        a1 += bfhi(u0.x) + bfhi(u1.x) + bfhi(u2.x) + bfhi(u3.x);
        a1 += bfhi(u4.x) + bfhi(u5.x) + bfhi(u6.x) + bfhi(u7.x);
        a2 += bflo(u0.y) + bflo(u1.y) + bflo(u2.y) + bflo(u3.y);
        a2 += bflo(u4.y) + bflo(u5.y) + bflo(u6.y) + bflo(u7.y);
        a3 += bfhi(u0.y) + bfhi(u1.y) + bfhi(u2.y) + bfhi(u3.y);
        a3 += bfhi(u4.y) + bfhi(u5.y) + bfhi(u6.y) + bfhi(u7.y);
        a4 += bflo(u0.z) + bflo(u1.z) + bflo(u2.z) + bflo(u3.z);
        a4 += bflo(u4.z) + bflo(u5.z) + bflo(u6.z) + bflo(u7.z);
        a5 += bfhi(u0.z) + bfhi(u1.z) + bfhi(u2.z) + bfhi(u3.z);
        a5 += bfhi(u4.z) + bfhi(u5.z) + bfhi(u6.z) + bfhi(u7.z);
        a6 += bflo(u0.w) + bflo(u1.w) + bflo(u2.w) + bflo(u3.w);
        a6 += bflo(u4.w) + bflo(u5.w) + bflo(u6.w) + bflo(u7.w);
        a7 += bfhi(u0.w) + bfhi(u1.w) + bfhi(u2.w) + bfhi(u3.w);
        a7 += bfhi(u4.w) + bfhi(u5.w) + bfhi(u6.w) + bfhi(u7.w);
    }
    if (e + 3 < e1) {
        int s0 = esrc[e], s1 = esrc[e + 1], s2 = esrc[e + 2], s3 = esrc[e + 3];
        e += 4;
        uint4 u0 = xb4[(size_t)s0 * 16 + l16];
        uint4 u1 = xb4[(size_t)s1 * 16 + l16];
        uint4 u2 = xb4[(size_t)s2 * 16 + l16];
        uint4 u3 = xb4[(size_t)s3 * 16 + l16];
        a0 += bflo(u0.x) + bflo(u1.x) + bflo(u2.x) + bflo(u3.x);
        a1 += bfhi(u0.x) + bfhi(u1.x) + bfhi(u2.x) + bfhi(u3.x);
        a2 += bflo(u0.y) + bflo(u1.y) + bflo(u2.y) + bflo(u3.y);
        a3 += bfhi(u0.y) + bfhi(u1.y) + bfhi(u2.y) + bfhi(u3.y);
        a4 += bflo(u0.z) + bflo(u1.z) + bflo(u2.z) + bflo(u3.z);
        a5 += bfhi(u0.z) + bfhi(u1.z) + bfhi(u2.z) + bfhi(u3.z);
        a6 += bflo(u0.w) + bflo(u1.w) + bflo(u2.w) + bflo(u3.w);
        a7 += bfhi(u0.w) + bfhi(u1.w) + bfhi(u2.w) + bfhi(u3.w);
    }
    for (; e < e1; ++e) {
        uint4 u = xb4[(size_t)esrc[e] * 16 + l16];
        a0 += bflo(u.x); a1 += bfhi(u.x); a2 += bflo(u.y); a3 += bfhi(u.y);
        a4 += bflo(u.z); a5 += bfhi(u.z); a6 += bflo(u.w); a7 += bfhi(u.w);
    }
    float di = dinv[node];
    a0 *= di; a1 *= di; a2 *= di; a3 *= di;
    a4 *= di; a5 *= di; a6 *= di; a7 *= di;
    int tile = r >> 6;
    int row_local = r & 63;
    int nhalf = row_local >> 5, nt = (row_local >> 4) & 1, l16r = row_local & 15;
    unsigned short* tbase = xaggF + (size_t)tile * 8192;
    size_t off = (size_t)(kc * 4 + nhalf * 2 + nt) * 512 + (quad * 16 + l16r) * 8;
    *(uint4*)(tbase + off) = make_uint4(pack2(a0, a1), pack2(a2, a3),
                                        pack2(a4, a5), pack2(a6, a7));
}

// ---------------- fused GEMM: h2s = bf16( dinv * (relu(xagg@W1+b1) @ W2) ) ----------------
// W-redundancy killed: xagg tile staged in LDS (unioned with Hs); phase 1 gives each
// wave an exclusive M-quarter (W1F read 1x/block, was 2x); phase 2 uses 2 waves x 32
// rows (W2F read 2x/block, was 4x). Per-block W+A traffic 280KB -> 144KB.
__launch_bounds__(256)
__global__ void k_fused_gemm(const unsigned short* __restrict__ AF,
                             const unsigned short* __restrict__ W1F,
                             const unsigned short* __restrict__ W2F,
                             const float* __restrict__ b1,
                             const float* __restrict__ dinv,
                             const int* __restrict__ perm,
                             unsigned short* __restrict__ h2b) {
    __shared__ __align__(16) unsigned char ldsbuf[64 * 268 * 2];  // 34304 B, unioned
    unsigned short* xaggL = (unsigned short*)ldsbuf;              // phase-1 A tile (16 KB)
    typedef unsigned short HsRow[268];
    HsRow* Hs = (HsRow*)ldsbuf;                                   // phase-2 H tile
    int tid = threadIdx.x;
    int w = tid >> 6, lane = tid & 63;
    int quad = lane >> 4, l16 = lane & 15;
    const unsigned short* AT = AF + (size_t)blockIdx.x * 8192;

    // stage xagg tile: coalesced 16B/thread x 4
#pragma unroll
    for (int it = 0; it < 4; ++it) {
        int idx = (it * 256 + tid) * 8;
        *(uint4*)(xaggL + idx) = *(const uint4*)(AT + idx);
    }
    __syncthreads();

    // ---- phase 1: wave w owns cols [w*64, w*64+64), all 64 rows ----
    f32x4 acc[4][4];  // [nt][mt]
#pragma unroll
    for (int nt = 0; nt < 4; nt++)
#pragma unroll
        for (int mt = 0; mt < 4; mt++) acc[nt][mt] = (f32x4){0.f, 0.f, 0.f, 0.f};

#pragma unroll
    for (int kc = 0; kc < 4; ++kc) {
        bf16x8 bf[4], af[4];
#pragma unroll
        for (int nt = 0; nt < 4; nt++)
            bf[nt] = *(const bf16x8*)(xaggL + (size_t)(kc * 4 + nt) * 512 + lane * 8);
#pragma unroll
        for (int mt = 0; mt < 4; mt++) {
            int mtg = w * 4 + mt;  // global 16-col tile, 0..15
            af[mt] = *(const bf16x8*)(W1F + (size_t)(((mtg >> 3) * 4 + kc) * 8 + (mtg & 7)) * 512 + lane * 8);
        }
#pragma unroll
        for (int nt = 0; nt < 4; nt++)
#pragma unroll
            for (int mt = 0; mt < 4; mt++)
                acc[nt][mt] = __builtin_amdgcn_mfma_f32_16x16x32_bf16(af[mt], bf[nt], acc[nt][mt], 0, 0, 0);
    }
    __syncthreads();  // all xaggL reads complete before Hs overwrites the union

#pragma unroll
    for (int mt = 0; mt < 4; mt++) {
        int colbase = (w * 4 + mt) * 16 + quad * 4;
        float4 bb = *(const float4*)(b1 + colbase);
#pragma unroll
        for (int nt = 0; nt < 4; nt++) {
            int nrow = nt * 16 + l16;
            float v0 = fmaxf(acc[nt][mt][0] + bb.x, 0.f);
            float v1 = fmaxf(acc[nt][mt][1] + bb.y, 0.f);
            float v2 = fmaxf(acc[nt][mt][2] + bb.z, 0.f);
            float v3 = fmaxf(acc[nt][mt][3] + bb.w, 0.f);
            *(uint2*)&Hs[nrow][colbase] = make_uint2(pack2(v0, v1), pack2(v2, v3));
        }
    }
    __syncthreads();

    // ---- phase 2: waves 0,1 only; wave w owns rows [w*32, w*32+32) ----
    if (w < 2) {
        f32x4 acc2[2][4];
#pragma unroll
        for (int nt = 0; nt < 2; nt++)
#pragma unroll
            for (int mt = 0; mt < 4; mt++) acc2[nt][mt] = (f32x4){0.f, 0.f, 0.f, 0.f};
#pragma unroll
        for (int kc = 0; kc < 8; ++kc) {
            int k0 = kc * 32;
            bf16x8 wf[4];
#pragma unroll
            for (int mt = 0; mt < 4; mt++)
                wf[mt] = *(const bf16x8*)(W2F + (size_t)(kc * 4 + mt) * 512 + lane * 8);
#pragma unroll
            for (int nt = 0; nt < 2; nt++) {
                int row = w * 32 + nt * 16 + l16;
                uint2 hlo = *(const uint2*)&Hs[row][k0 + quad * 8];
                uint2 hhi = *(const uint2*)&Hs[row][k0 + quad * 8 + 4];
                union { uint4 u; bf16x8 b; } hc;
                hc.u = make_uint4(hlo.x, hlo.y, hhi.x, hhi.y);
#pragma unroll
                for (int mt = 0; mt < 4; mt++)
                    acc2[nt][mt] = __builtin_amdgcn_mfma_f32_16x16x32_bf16(wf[mt], hc.b, acc2[nt][mt], 0, 0, 0);
            }
        }
#pragma unroll
        for (int nt = 0; nt < 2; nt++) {
            int grow = blockIdx.x * 64 + w * 32 + nt * 16 + l16;  // perm position
            if (grow < N_NODES) {
                int node = perm[grow];
                float dg = dinv[node];
#pragma unroll
                for (int mt = 0; mt < 3; mt++) {  // only cols < 40 stored (stride-40 h2b)
                    int col = mt * 16 + quad * 4;
                    if (col < F_OUT) {
                        uint2 o = make_uint2(pack2(dg * acc2[nt][mt][0], dg * acc2[nt][mt][1]),
                                             pack2(dg * acc2[nt][mt][2], dg * acc2[nt][mt][3]));
                        *(uint2*)(h2b + (size_t)node * 40 + col) = o;
                    }
                }
            }
        }
    }
}

// ---------------- layer 2 aggregation + bias + log_softmax ----------------
// 5 lanes/node (60/64 active), 12 nodes/wave, 48 nodes/block; pipelined 8-edge unroll.
__global__ void k_agg2(const uint4* __restrict__ h2v4, const float* __restrict__ dinv,
                       const int* __restrict__ rowstart,
                       const int* __restrict__ esrc, const int* __restrict__ perm,
                       const float* __restrict__ b2, float* __restrict__ out) {
    int t = threadIdx.x;
    int wv = t >> 6, lane = t & 63;
    int grp = lane / 5;          // 0..11 active, 12 = lanes 60..63 idle
    int c = lane - grp * 5;      // chunk 0..4
    int r = blockIdx.x * 48 + wv * 12 + grp;
    bool act = (grp < 12) && (r < N_NODES);
    int node = act ? perm[r] : 0;
    float a0 = 0.f, a1 = 0.f, a2 = 0.f, a3 = 0.f, a4 = 0.f, a5 = 0.f, a6 = 0.f, a7 = 0.f;
    if (act) {
        uint4 v = h2v4[(size_t)node * 5 + c];  // self term (pre-scaled)
        a0 = bflo(v.x); a1 = bfhi(v.x); a2 = bflo(v.y); a3 = bfhi(v.y);
        a4 = bflo(v.z); a5 = bfhi(v.z); a6 = bflo(v.w); a7 = bfhi(v.w);
        int e0 = rowstart[node];
        int e1 = rowstart[node + 1];
        int e = e0;
        int p0, p1, p2, p3, p4, p5, p6, p7;
        if (e + 7 < e1) {
            p0 = esrc[e];     p1 = esrc[e + 1]; p2 = esrc[e + 2]; p3 = esrc[e + 3];
            p4 = esrc[e + 4]; p5 = esrc[e + 5]; p6 = esrc[e + 6]; p7 = esrc[e + 7];
        }
        while (e + 7 < e1) {
            int s0 = p0, s1 = p1, s2 = p2, s3 = p3, s4 = p4, s5 = p5, s6 = p6, s7 = p7;
            e += 8;
            if (e + 7 < e1) {
                p0 = esrc[e];     p1 = esrc[e + 1]; p2 = esrc[e + 2]; p3 = esrc[e + 3];
                p4 = esrc[e + 4]; p5 = esrc[e + 5]; p6 = esrc[e + 6]; p7 = esrc[e + 7];
            }
            uint4 u0 = h2v4[(size_t)s0 * 5 + c];
            uint4 u1 = h2v4[(size_t)s1 * 5 + c];
            uint4 u2 = h2v4[(size_t)s2 * 5 + c];
            uint4 u3 = h2v4[(size_t)s3 * 5 + c];
            uint4 u4 = h2v4[(size_t)s4 * 5 + c];
            uint4 u5 = h2v4[(size_t)s5 * 5 + c];
            uint4 u6 = h2v4[(size_t)s6 * 5 + c];
            uint4 u7 = h2v4[(size_t)s7 * 5 + c];
            a0 += bflo(u0.x) + bflo(u1.x) + bflo(u2.x) + bflo(u3.x);
            a0 += bflo(u4.x) + bflo(u5.x) + bflo(u6.x) + bflo(u7.x);
            a1 += bfhi(u0.x) + bfhi(u1.x) + bfhi(u2.x) + bfhi(u3.x);
            a1 += bfhi(u4.x) + bfhi(u5.x) + bfhi(u6.x) + bfhi(u7.x);
            a2 += bflo(u0.y) + bflo(u1.y) + bflo(u2.y) + bflo(u3.y);
            a2 += bflo(u4.y) + bflo(u5.y) + bflo(u6.y) + bflo(u7.y);
            a3 += bfhi(u0.y) + bfhi(u1.y) + bfhi(u2.y) + bfhi(u3.y);
            a3 += bfhi(u4.y) + bfhi(u5.y) + bfhi(u6.y) + bfhi(u7.y);
            a4 += bflo(u0.z) + bflo(u1.z) + bflo(u2.z) + bflo(u3.z);
            a4 += bflo(u4.z) + bflo(u5.z) + bflo(u6.z) + bflo(u7.z);
            a5 += bfhi(u0.z) + bfhi(u1.z) + bfhi(u2.z) + bfhi(u3.z);
            a5 += bfhi(u4.z) + bfhi(u5.z) + bfhi(u6.z) + bfhi(u7.z);
            a6 += bflo(u0.w) + bflo(u1.w) + bflo(u2.w) + bflo(u3.w);
            a6 += bflo(u4.w) + bflo(u5.w) + bflo(u6.w) + bflo(u7.w);
            a7 += bfhi(u0.w) + bfhi(u1.w) + bfhi(u2.w) + bfhi(u3.w);
            a7 += bfhi(u4.w) + bfhi(u5.w) + bfhi(u6.w) + bfhi(u7.w);
        }
        if (e + 3 < e1) {
            int s0 = esrc[e], s1 = esrc[e + 1], s2 = esrc[e + 2], s3 = esrc[e + 3];
            e += 4;
            uint4 u0 = h2v4[(size_t)s0 * 5 + c];
            uint4 u1 = h2v4[(size_t)s1 * 5 + c];
            uint4 u2 = h2v4[(size_t)s2 * 5 + c];
            uint4 u3 = h2v4[(size_t)s3 * 5 + c];
            a0 += bflo(u0.x) + bflo(u1.x) + bflo(u2.x) + bflo(u3.x);
            a1 += bfhi(u0.x) + bfhi(u1.x) + bfhi(u2.x) + bfhi(u3.x);
            a2 += bflo(u0.y) + bflo(u1.y) + bflo(u2.y) + bflo(u3.y);
            a3 += bfhi(u0.y) + bfhi(u1.y) + bfhi(u2.y) + bfhi(u3.y);
            a4 += bflo(u0.z) + bflo(u1.z) + bflo(u2.z) + bflo(u3.z);
            a5 += bfhi(u0.z) + bfhi(u1.z) + bfhi(u2.z) + bfhi(u3.z);
            a6 += bflo(u0.w) + bflo(u1.w) + bflo(u2.w) + bflo(u3.w);
            a7 += bfhi(u0.w) + bfhi(u1.w) + bfhi(u2.w) + bfhi(u3.w);
        }
        for (; e < e1; ++e) {
            uint4 u = h2v4[(size_t)esrc[e] * 5 + c];
            a0 += bflo(u.x); a1 += bfhi(u.x); a2 += bflo(u.y); a3 += bfhi(u.y);
            a4 += bflo(u.z); a5 += bfhi(u.z); a6 += bflo(u.w); a7 += bfhi(u.w);
        }
    }
    float di = dinv[node];
    float vals[8];
    if (act) {
        float4 bA = *(const float4*)(b2 + 8 * c);
        float4 bB = *(const float4*)(b2 + 8 * c + 4);
        vals[0] = di * a0 + bA.x; vals[1] = di * a1 + bA.y;
        vals[2] = di * a2 + bA.z; vals[3] = di * a3 + bA.w;
        vals[4] = di * a4 + bB.x; vals[5] = di * a5 + bB.y;
        vals[6] = di * a6 + bB.z; vals[7] = di * a7 + bB.w;
    } else {
#pragma unroll
        for (int j = 0; j < 8; j++) vals[j] = -3.0e38f;
    }
    float pm = vals[0];
#pragma unroll
    for (int j = 1; j < 8; j++) pm = fmaxf(pm, vals[j]);
    float m = pm;
#pragma unroll
    for (int k = 1; k < 5; k++) {
        int srcl = grp * 5 + ((c + k) % 5);
        srcl = srcl > 63 ? 63 : srcl;
        m = fmaxf(m, __shfl(pm, srcl));
    }
    float ps = 0.0f;
    if (act) {
#pragma unroll
        for (int j = 0; j < 8; j++) ps += __expf(vals[j] - m);
    }
    float s = ps;
#pragma unroll
    for (int k = 1; k < 5; k++) {
        int srcl = grp * 5 + ((c + k) % 5);
        srcl = srcl > 63 ? 63 : srcl;
        s += __shfl(ps, srcl);
    }
    float logs = logf(s);
    if (act) {
        float o0[4] = {vals[0] - m - logs, vals[1] - m - logs, vals[2] - m - logs, vals[3] - m - logs};
        float o1[4] = {vals[4] - m - logs, vals[5] - m - logs, vals[6] - m - logs, vals[7] - m - logs};
        float* ob = out + (size_t)node * F_OUT + 8 * c;
        *(float4*)ob = *(float4*)o0;
        *(float4*)(ob + 4) = *(float4*)o1;
    }
}

// ---------------- launch ----------------

extern "C" void kernel_launch(void* const* d_in, const int* in_sizes, int n_in,
                              void* d_out, int out_size, void* d_ws, size_t ws_size,
                              hipStream_t stream) {
    const float* x  = (const float*)d_in[0];
    const int* edge = (const int*)d_in[1];
    const float* W1 = (const float*)d_in[2];
    const float* b1 = (const float*)d_in[3];
    const float* W2 = (const float*)d_in[4];
    const float* b2 = (const float*)d_in[5];
    float* out = (float*)d_out;
    const int* src = edge;
    const int* dst = edge + N_EDGES;

    char* ws = (char*)d_ws;
    size_t off = 0;
    auto alloc = [&](size_t bytes) -> void* {
        void* p = ws + off;
        off = (off + bytes + 255) & ~(size_t)255;
        return p;
    };
    int* bcur     = (int*)alloc((size_t)(NB + 128) * 4);  // bcur[NB] + dhist[64] + dcnt[64]
    int* dhist    = bcur + NB;
    int* dcnt     = bcur + NB + 64;
    unsigned int* part = (unsigned int*)alloc((size_t)NB * BCAP * 4);
    float* dinv   = (float*)alloc((size_t)N_NODES * 4);
    int* cnt      = (int*)alloc((size_t)N_NODES * 4);
    int* rowstart = (int*)alloc((size_t)(N_NODES + 1) * 4);
    int* perm     = (int*)alloc((size_t)N_NODES * 4);
    int* esrc     = (int*)alloc((size_t)N_EDGES * 4);
    unsigned int* xb       = (unsigned int*)alloc((size_t)N_NODES * F_IN * 2);
    unsigned short* xaggF  = (unsigned short*)alloc((size_t)N_TILES * 8192 * 2);
    unsigned short* W1F    = (unsigned short*)alloc((size_t)32768 * 2);
    unsigned short* W2F    = (unsigned short*)alloc((size_t)16384 * 2);
    unsigned short* h2b    = (unsigned short*)alloc((size_t)N_NODES * 40 * 2);  // stride-40
    (void)ws_size; (void)in_sizes; (void)n_in; (void)out_size;

    hipMemsetAsync(bcur, 0, (size_t)(NB + 128) * 4, stream);
    hipLaunchKernelGGL(k_part, dim3(PART_BLOCKS), dim3(256), 0, stream,
                       src, dst, bcur, part);
    hipLaunchKernelGGL(k_bucket, dim3(NB), dim3(256), 0, stream,
                       part, bcur, rowstart, dinv, cnt, dhist, esrc);
    hipLaunchKernelGGL(k_fill_cast, dim3(12790), dim3(256), 0, stream,
                       x, dinv, (uint2*)xb, W1, W2, W1F, W2F, cnt, dhist, dcnt, perm);
    hipLaunchKernelGGL(k_agg1, dim3(N_NODES / 16), dim3(256), 0, stream,
                       (const uint4*)xb, dinv, rowstart, esrc, perm, xaggF);
    hipLaunchKernelGGL(k_fused_gemm, dim3(N_TILES), dim3(256), 0, stream,
                       xaggF, W1F, W2F, b1, dinv, perm, h2b);
    hipLaunchKernelGGL(k_agg2, dim3((N_NODES + 47) / 48), dim3(256), 0, stream,
                       (const uint4*)h2b, dinv, rowstart, esrc, perm, b2, out);
}